// Round 1
// baseline (866.230 us; speedup 1.0000x reference)
//
#include <hip/hip_runtime.h>

// Conv2dInt8: x(8,32,512,512) fp32, w(32,32,3,3) int32(uint8-like), bias(32) int32
// y = relu(dequant(requant(conv(quant(x), w-128) + bias)))
// Implicit-GEMM with mfma_f32_16x16x32_bf16: M=16 spatial, N=16 cout, K=32 cin.
// All integer values are exact in bf16; fp32 accumulation exact (|sum| < 2^24).

#define N_IMG 8
#define CIN   32
#define COUT  32
#define HD    512
#define WD    512
#define TW    64   // spatial w per block (4 waves x 16)
#define TH    8    // output rows per block

typedef short short8 __attribute__((ext_vector_type(8)));
typedef float floatx4 __attribute__((ext_vector_type(4)));

__launch_bounds__(256, 2)
__global__ void conv2d_int8_kernel(const float* __restrict__ x,
                                   const int* __restrict__ wq,
                                   const int* __restrict__ bias,
                                   float* __restrict__ out)
{
    // xs: [r(10)][wc(66)][cin(32)] bf16 bits, cin-groups-of-8 XOR-swizzled by (pix&3)
    __shared__ unsigned short xs[10 * 66 * 32];   // 42240 B
    // ws: [tap(9)][cout(32)][cin(32)] bf16 bits
    __shared__ unsigned short ws[9 * 32 * 32];    // 18432 B

    const int tid = threadIdx.x;
    const int bx = blockIdx.x;   // w tile: 0..7
    const int by = blockIdx.y;   // h tile: 0..63
    const int n  = blockIdx.z;   // image: 0..7

    // ---- stage weights (recenter, cast to bf16 bits) ----
    for (int i = tid; i < COUT * CIN * 9; i += 256) {
        int cout = i / 288;
        int rem  = i - cout * 288;
        int cin  = rem / 9;
        int t    = rem - cin * 9;          // kh*3+kw
        float f = (float)(wq[i] - 128);
        unsigned short b = (unsigned short)(__float_as_uint(f) >> 16);
        ws[(t * 32 + cout) * 32 + cin] = b;
    }

    // ---- stage input tile: quantize fp32 -> int (exact) -> bf16 bits, transpose to [pix][cin] ----
    const int h_base = by * TH - 1;
    const int w_base = bx * TW - 1;
    for (int j = tid; j < CIN * 10 * 66; j += 256) {
        int c   = j / 660;
        int rem = j - c * 660;
        int r   = rem / 66;
        int wc  = rem - r * 66;
        int h = h_base + r;
        int w = w_base + wc;
        float q = 0.0f;
        if ((unsigned)h < (unsigned)HD && (unsigned)w < (unsigned)WD) {
            float xv = x[((n * CIN + c) * HD + h) * WD + w];
            q = rintf(xv / 0.05f);                 // match numpy: fp32 divide, round-half-even
            q = fminf(fmaxf(q, -128.0f), 127.0f);  // clip to [0,255]-128
        }
        unsigned short b = (unsigned short)(__float_as_uint(q) >> 16);
        int pix = r * 66 + wc;
        int grp = (c >> 3) ^ (pix & 3);            // bank-conflict swizzle, keeps 16B align
        xs[pix * 32 + (grp << 3) + (c & 7)] = b;
    }
    __syncthreads();

    const int lane = tid & 63;
    const int wave = tid >> 6;
    const int l15  = lane & 15;
    const int quad = lane >> 4;

    // ---- B fragments: B[k=cin][n=cout], lane holds 8 cin at k0=quad*8 for cout=half*16+l15 ----
    short8 bfrag[9][2];
#pragma unroll
    for (int t = 0; t < 9; ++t) {
#pragma unroll
        for (int hf = 0; hf < 2; ++hf) {
            int cout = hf * 16 + l15;
            bfrag[t][hf] = *(const short8*)&ws[(t * 32 + cout) * 32 + quad * 8];
        }
    }

    const float b0 = (float)bias[l15];
    const float b1 = (float)bias[16 + l15];
    const int wseg = wave * 16;      // this wave's spatial base within the tile

    for (int hr = 0; hr < TH; ++hr) {
        floatx4 acc0 = {0.f, 0.f, 0.f, 0.f};
        floatx4 acc1 = {0.f, 0.f, 0.f, 0.f};
#pragma unroll
        for (int kh = 0; kh < 3; ++kh) {
#pragma unroll
            for (int kw = 0; kw < 3; ++kw) {
                int pix = (hr + kh) * 66 + wseg + l15 + kw;   // A: m=l15, k-block=quad
                int grp = quad ^ (pix & 3);
                short8 a = *(const short8*)&xs[pix * 32 + (grp << 3)];
                int t = kh * 3 + kw;
                acc0 = __builtin_amdgcn_mfma_f32_16x16x32_bf16(a, bfrag[t][0], acc0, 0, 0, 0);
                acc1 = __builtin_amdgcn_mfma_f32_16x16x32_bf16(a, bfrag[t][1], acc1, 0, 0, 0);
            }
        }
        // ---- epilogue: +bias, requant, dequant, relu, store ----
        // C/D layout: col(n=cout)=l15, row(m=spatial)=quad*4+r  [verified m89/m91]
        const int h_out = by * TH + hr;
        const int w_out0 = bx * TW + wseg;
#pragma unroll
        for (int r = 0; r < 4; ++r) {
            int wo = w_out0 + quad * 4 + r;
            {
                float v = acc0[r] + b0;
                float yq = rintf(v * 0.01f);
                yq = fminf(fmaxf(yq, -127.f), 127.f);
                float y = fmaxf(yq * 0.1f, 0.f);
                out[((n * COUT + l15) * HD + h_out) * WD + wo] = y;
            }
            {
                float v = acc1[r] + b1;
                float yq = rintf(v * 0.01f);
                yq = fminf(fmaxf(yq, -127.f), 127.f);
                float y = fmaxf(yq * 0.1f, 0.f);
                out[((n * COUT + 16 + l15) * HD + h_out) * WD + wo] = y;
            }
        }
    }
}

extern "C" void kernel_launch(void* const* d_in, const int* in_sizes, int n_in,
                              void* d_out, int out_size, void* d_ws, size_t ws_size,
                              hipStream_t stream) {
    const float* x  = (const float*)d_in[0];
    const int*   wq = (const int*)d_in[1];
    const int*   bi = (const int*)d_in[2];
    float* out = (float*)d_out;
    dim3 grid(WD / TW, HD / TH, N_IMG);   // 8 x 64 x 8 = 4096 blocks
    conv2d_int8_kernel<<<grid, dim3(256), 0, stream>>>(x, wq, bi, out);
}

// Round 2
// 606.851 us; speedup vs baseline: 1.4274x; 1.4274x over previous
//
#include <hip/hip_runtime.h>

// Conv2dInt8: x(8,32,512,512) fp32, w(32,32,3,3) int32(uint8-like), bias(32) int32
// Pipeline: (1) quantize fp32 NCHW -> bf16 padded-NHWC in d_ws,
//           (2) zero halo border + bf16 weights [tap][cout][cin],
//           (3) LDS-free implicit-GEMM conv with mfma_f32_16x16x32_bf16
//               (A=weights m=cout, B=activations n=w-pixel, K=cin=32).
// Integer values exact in bf16; fp32 accumulation exact (|sum| < 2^24).

#define N_IMG 8
#define CIN   32
#define COUT  32
#define HD    512
#define WD    512
#define PH    514   // padded
#define PW    514
#define TH    8     // output rows per conv block

typedef short short8 __attribute__((ext_vector_type(8)));
typedef float floatx4 __attribute__((ext_vector_type(4)));

#define XQ_USHORTS ((size_t)N_IMG * PH * PW * CIN)           // 67,634,176
#define WS_NEED    ((XQ_USHORTS + (size_t)9 * 32 * 32) * 2)  // 135,286,784 B

// ---------------- dispatch 1: quantize + transpose to padded NHWC bf16 ----------------
__global__ __launch_bounds__(256) void quant_kernel(const float* __restrict__ x,
                                                    unsigned short* __restrict__ xq) {
    const int gid = blockIdx.x * 256 + threadIdx.x;     // over n*h*w = 8*512*512
    const int w = gid & (WD - 1);
    const int h = (gid >> 9) & (HD - 1);
    const int n = gid >> 18;
    const float* xp = x + ((size_t)n * CIN * HD + h) * WD + w;   // c-stride = HD*WD
    unsigned int pk[16];
#pragma unroll
    for (int c = 0; c < CIN; c += 2) {
        float a = xp[(size_t)c * (HD * WD)];
        float b = xp[(size_t)(c + 1) * (HD * WD)];
        float qa = rintf(a / 0.05f);                 // identical numerics to R1 (passed)
        qa = fminf(fmaxf(qa, -128.0f), 127.0f);
        float qb = rintf(b / 0.05f);
        qb = fminf(fmaxf(qb, -128.0f), 127.0f);
        pk[c >> 1] = (__float_as_uint(qa) >> 16) | (__float_as_uint(qb) & 0xffff0000u);
    }
    uint4* dst = (uint4*)(xq + (((size_t)n * PH + h + 1) * PW + (w + 1)) * CIN);
#pragma unroll
    for (int i = 0; i < 4; ++i)
        dst[i] = make_uint4(pk[4 * i], pk[4 * i + 1], pk[4 * i + 2], pk[4 * i + 3]);
}

// ---------------- dispatch 2: border zero + weight bf16 repack ----------------
#define N_BORDER (N_IMG * 2052)     // (2*514 + 2*512) pixels per image
#define N_WELEM  (COUT * CIN * 9)
__global__ __launch_bounds__(256) void aux_kernel(const int* __restrict__ wq,
                                                  unsigned short* __restrict__ xq,
                                                  unsigned short* __restrict__ wb) {
    const int gid = blockIdx.x * 256 + threadIdx.x;
    if (gid < N_BORDER) {
        const int n = gid / 2052;
        const int p = gid - n * 2052;
        int h, w;
        if (p < 514)       { h = 0;   w = p; }
        else if (p < 1028) { h = 513; w = p - 514; }
        else { int q = p - 1028; h = 1 + (q >> 1); w = (q & 1) ? 513 : 0; }
        uint4* dst = (uint4*)(xq + (((size_t)n * PH + h) * PW + w) * CIN);
        uint4 z = make_uint4(0u, 0u, 0u, 0u);
        dst[0] = z; dst[1] = z; dst[2] = z; dst[3] = z;
    } else if (gid < N_BORDER + N_WELEM) {
        const int i = gid - N_BORDER;
        const int cout = i / 288;
        const int rem  = i - cout * 288;
        const int cin  = rem / 9;
        const int t    = rem - cin * 9;          // kh*3+kw
        float f = (float)(wq[i] - 128);
        wb[(t * 32 + cout) * 32 + cin] = (unsigned short)(__float_as_uint(f) >> 16);
    }
}

// ---------------- dispatch 3: conv, LDS-free, barrier-free ----------------
__global__ __launch_bounds__(256, 4) void conv_kernel(const unsigned short* __restrict__ xq,
                                                      const unsigned short* __restrict__ wb,
                                                      const int* __restrict__ bias,
                                                      float* __restrict__ out) {
    const int tid  = threadIdx.x;
    const int lane = tid & 63;
    const int wave = tid >> 6;
    const int l15  = lane & 15;
    const int quad = lane >> 4;
    const int bx = blockIdx.x;   // w tile: 0..7 (64 pixels)
    const int by = blockIdx.y;   // h tile: 0..63 (TH rows)
    const int n  = blockIdx.z;

    // A-fragments (weights): lane l15 = cout(m), quad = cin-group(k). L2-resident.
    short8 wf[9][2];
#pragma unroll
    for (int t = 0; t < 9; ++t) {
        wf[t][0] = *(const short8*)&wb[(t * 32 + l15) * 32 + quad * 8];
        wf[t][1] = *(const short8*)&wb[(t * 32 + 16 + l15) * 32 + quad * 8];
    }
    // bias for this lane's 8 couts (rows quad*4+r and 16+quad*4+r)
    const int4 bi0 = *(const int4*)&bias[quad * 4];
    const int4 bi1 = *(const int4*)&bias[16 + quad * 4];
    float fb0[4] = {(float)bi0.x, (float)bi0.y, (float)bi0.z, (float)bi0.w};
    float fb1[4] = {(float)bi1.x, (float)bi1.y, (float)bi1.z, (float)bi1.w};

    const int w0 = bx * 64 + wave * 16;      // this wave's 16 output pixels: w0 + l15

    for (int hr = 0; hr < TH; ++hr) {
        const int h = by * TH + hr;
        // padded coords: row h+kh, col (w0+l15)+kw  (center offset +1 built into padding)
        const unsigned short* pb = xq + (((size_t)n * PH + h) * PW + (w0 + l15)) * CIN + quad * 8;
        floatx4 acc0 = {0.f, 0.f, 0.f, 0.f};
        floatx4 acc1 = {0.f, 0.f, 0.f, 0.f};
#pragma unroll
        for (int kh = 0; kh < 3; ++kh) {
#pragma unroll
            for (int kw = 0; kw < 3; ++kw) {
                short8 a = *(const short8*)(pb + (kh * PW + kw) * CIN);  // B-frag: n=pixel, k=cin
                const int t = kh * 3 + kw;
                acc0 = __builtin_amdgcn_mfma_f32_16x16x32_bf16(wf[t][0], a, acc0, 0, 0, 0);
                acc1 = __builtin_amdgcn_mfma_f32_16x16x32_bf16(wf[t][1], a, acc1, 0, 0, 0);
            }
        }
        // D layout: col(n=pixel)=l15, row(m=cout)=quad*4+r  -> 16-lane contiguous stores
        float* op0 = out + (((size_t)n * COUT + quad * 4) * HD + h) * WD + w0 + l15;
        float* op1 = out + (((size_t)n * COUT + 16 + quad * 4) * HD + h) * WD + w0 + l15;
#pragma unroll
        for (int r = 0; r < 4; ++r) {
            float v = acc0[r] + fb0[r];
            float yq = rintf(v * 0.01f);
            yq = fminf(fmaxf(yq, -127.f), 127.f);
            op0[(size_t)r * (HD * WD)] = fmaxf(yq * 0.1f, 0.f);
        }
#pragma unroll
        for (int r = 0; r < 4; ++r) {
            float v = acc1[r] + fb1[r];
            float yq = rintf(v * 0.01f);
            yq = fminf(fmaxf(yq, -127.f), 127.f);
            op1[(size_t)r * (HD * WD)] = fmaxf(yq * 0.1f, 0.f);
        }
    }
}

// ---------------- fallback (R1 kernel) if workspace too small ----------------
__launch_bounds__(256, 2)
__global__ void conv2d_int8_fused(const float* __restrict__ x,
                                  const int* __restrict__ wq,
                                  const int* __restrict__ bias,
                                  float* __restrict__ out)
{
    __shared__ unsigned short xs[10 * 66 * 32];
    __shared__ unsigned short ws[9 * 32 * 32];
    const int tid = threadIdx.x;
    const int bx = blockIdx.x, by = blockIdx.y, n = blockIdx.z;
    for (int i = tid; i < COUT * CIN * 9; i += 256) {
        int cout = i / 288, rem = i - cout * 288, cin = rem / 9, t = rem - cin * 9;
        float f = (float)(wq[i] - 128);
        ws[(t * 32 + cout) * 32 + cin] = (unsigned short)(__float_as_uint(f) >> 16);
    }
    const int h_base = by * TH - 1;
    const int w_base = bx * 64 - 1;
    for (int j = tid; j < CIN * 10 * 66; j += 256) {
        int c = j / 660, rem = j - c * 660, r = rem / 66, wc = rem - r * 66;
        int h = h_base + r, w = w_base + wc;
        float q = 0.0f;
        if ((unsigned)h < (unsigned)HD && (unsigned)w < (unsigned)WD) {
            float xv = x[((size_t)(n * CIN + c) * HD + h) * WD + w];
            q = rintf(xv / 0.05f);
            q = fminf(fmaxf(q, -128.0f), 127.0f);
        }
        unsigned short b = (unsigned short)(__float_as_uint(q) >> 16);
        int pix = r * 66 + wc;
        int grp = (c >> 3) ^ (pix & 3);
        xs[pix * 32 + (grp << 3) + (c & 7)] = b;
    }
    __syncthreads();
    const int lane = tid & 63, wave = tid >> 6;
    const int l15 = lane & 15, quad = lane >> 4;
    short8 bfrag[9][2];
#pragma unroll
    for (int t = 0; t < 9; ++t)
#pragma unroll
        for (int hf = 0; hf < 2; ++hf)
            bfrag[t][hf] = *(const short8*)&ws[(t * 32 + hf * 16 + l15) * 32 + quad * 8];
    const float b0 = (float)bias[l15];
    const float b1 = (float)bias[16 + l15];
    const int wseg = wave * 16;
    for (int hr = 0; hr < TH; ++hr) {
        floatx4 acc0 = {0.f, 0.f, 0.f, 0.f};
        floatx4 acc1 = {0.f, 0.f, 0.f, 0.f};
#pragma unroll
        for (int kh = 0; kh < 3; ++kh)
#pragma unroll
            for (int kw = 0; kw < 3; ++kw) {
                int pix = (hr + kh) * 66 + wseg + l15 + kw;
                int grp = quad ^ (pix & 3);
                short8 a = *(const short8*)&xs[pix * 32 + (grp << 3)];
                int t = kh * 3 + kw;
                acc0 = __builtin_amdgcn_mfma_f32_16x16x32_bf16(a, bfrag[t][0], acc0, 0, 0, 0);
                acc1 = __builtin_amdgcn_mfma_f32_16x16x32_bf16(a, bfrag[t][1], acc1, 0, 0, 0);
            }
        const int h_out = by * TH + hr;
        const int w_out0 = bx * 64 + wseg;
#pragma unroll
        for (int r = 0; r < 4; ++r) {
            int wo = w_out0 + quad * 4 + r;
            {
                float v = acc0[r] + b0;
                float yq = rintf(v * 0.01f);
                yq = fminf(fmaxf(yq, -127.f), 127.f);
                out[((size_t)(n * COUT + l15) * HD + h_out) * WD + wo] = fmaxf(yq * 0.1f, 0.f);
            }
            {
                float v = acc1[r] + b1;
                float yq = rintf(v * 0.01f);
                yq = fminf(fmaxf(yq, -127.f), 127.f);
                out[((size_t)(n * COUT + 16 + l15) * HD + h_out) * WD + wo] = fmaxf(yq * 0.1f, 0.f);
            }
        }
    }
}

extern "C" void kernel_launch(void* const* d_in, const int* in_sizes, int n_in,
                              void* d_out, int out_size, void* d_ws, size_t ws_size,
                              hipStream_t stream) {
    const float* x  = (const float*)d_in[0];
    const int*   wq = (const int*)d_in[1];
    const int*   bi = (const int*)d_in[2];
    float* out = (float*)d_out;

    if (ws_size >= WS_NEED) {
        unsigned short* xq = (unsigned short*)d_ws;
        unsigned short* wb = xq + XQ_USHORTS;
        aux_kernel<<<(N_BORDER + N_WELEM + 255) / 256, 256, 0, stream>>>(wq, xq, wb);
        quant_kernel<<<(N_IMG * HD * WD) / 256, 256, 0, stream>>>(x, xq);
        conv_kernel<<<dim3(WD / 64, HD / TH, N_IMG), dim3(256), 0, stream>>>(xq, wb, bi, out);
    } else {
        conv2d_int8_fused<<<dim3(WD / 64, HD / TH, N_IMG), dim3(256), 0, stream>>>(x, wq, bi, out);
    }
}

// Round 3
// 523.209 us; speedup vs baseline: 1.6556x; 1.1599x over previous
//
#include <hip/hip_runtime.h>

// Conv2dInt8: x(8,32,512,512) fp32, w(32,32,3,3) int32(uint8-like), bias(32) int32
// R3: int8 pipeline with mfma_i32_16x16x64_i8 (exact int32 arithmetic).
//  (1) quant: fp32 NCHW -> int8 padded NHWC in d_ws (halves intermediate traffic)
//  (2) aux:   zero halo border + pack weights [kh][kwpair][cout][64] int8
//             (K=64 = 2 kw-taps x 32 cin; pair (kw=2,kw=3) zero-padded)
//  (3) conv:  LDS-free, 2-row unroll with row reuse + prefetch:
//             4 x 16B loads per 2 output rows, 24 MFMAs/iter.

#define N_IMG 8
#define CIN   32
#define COUT  32
#define HD    512
#define WD    512
#define PH    514
#define PW    514
#define TH    8

typedef int intx4 __attribute__((ext_vector_type(4)));
typedef short short8 __attribute__((ext_vector_type(8)));
typedef float floatx4 __attribute__((ext_vector_type(4)));

#define XQ_BYTES ((size_t)N_IMG * PH * PW * CIN)   // 67,634,176
#define SLACK    256                               // pair-1 reads up to 64B past last pixel
#define WP_BYTES (6 * 32 * 64)                     // 12,288
#define WS_NEED  (XQ_BYTES + SLACK + WP_BYTES)

// ---------------- dispatch 1: quantize fp32 NCHW -> int8 padded NHWC ----------------
__global__ __launch_bounds__(256) void quant8_kernel(const float* __restrict__ x,
                                                     unsigned char* __restrict__ xq) {
    const int gid = blockIdx.x * 256 + threadIdx.x;     // over n*h*w
    const int w = gid & (WD - 1);
    const int h = (gid >> 9) & (HD - 1);
    const int n = gid >> 18;
    const float* xp = x + ((size_t)n * CIN * HD + h) * WD + w;
    unsigned int pk[8];
#pragma unroll
    for (int c = 0; c < CIN; c += 4) {
        unsigned int b[4];
#pragma unroll
        for (int j = 0; j < 4; ++j) {
            float xv = xp[(size_t)(c + j) * (HD * WD)];
            float q = rintf(xv / 0.05f);                 // identical numerics to R1/R2 (passed)
            q = fminf(fmaxf(q, -128.0f), 127.0f);
            b[j] = (unsigned int)(int)q & 0xffu;
        }
        pk[c >> 2] = b[0] | (b[1] << 8) | (b[2] << 16) | (b[3] << 24);
    }
    uint4* dst = (uint4*)(xq + (((size_t)n * PH + h + 1) * PW + (w + 1)) * CIN);
    dst[0] = make_uint4(pk[0], pk[1], pk[2], pk[3]);
    dst[1] = make_uint4(pk[4], pk[5], pk[6], pk[7]);
}

// ---------------- dispatch 2: border zero + weight int8 pack ----------------
#define N_BORDER (N_IMG * 2052)
#define N_WP     (6 * 32 * 64)
__global__ __launch_bounds__(256) void aux8_kernel(const int* __restrict__ wq,
                                                   unsigned char* __restrict__ xq,
                                                   char* __restrict__ wp) {
    const int gid = blockIdx.x * 256 + threadIdx.x;
    if (gid < N_BORDER) {
        const int n = gid / 2052;
        const int p = gid - n * 2052;
        int h, w;
        if (p < 514)       { h = 0;   w = p; }
        else if (p < 1028) { h = 513; w = p - 514; }
        else { int q = p - 1028; h = 1 + (q >> 1); w = (q & 1) ? 513 : 0; }
        uint4* dst = (uint4*)(xq + (((size_t)n * PH + h) * PW + w) * CIN);
        uint4 z = make_uint4(0u, 0u, 0u, 0u);
        dst[0] = z; dst[1] = z;
    } else if (gid < N_BORDER + N_WP) {
        const int i = gid - N_BORDER;
        // wp[(kh*2+pair)*32 + cout][k], k = sel*32 + cin, kw = pair*2 + sel
        const int row  = i >> 6;
        const int k    = i & 63;
        const int khp  = row >> 5;        // 0..5
        const int cout = row & 31;
        const int kh   = khp >> 1;
        const int pr   = khp & 1;
        const int sel  = k >> 5;
        const int cin  = k & 31;
        const int kw   = pr * 2 + sel;
        int val = 0;
        if (kw < 3) val = wq[((cout * CIN + cin) * 3 + kh) * 3 + kw] - 128;  // OIHW
        wp[i] = (char)val;
    }
}

// ---------------- dispatch 3: conv, LDS-free, i8 MFMA, 2-row unroll ----------------
__global__ __launch_bounds__(256, 3) void conv8_kernel(const unsigned char* __restrict__ xq,
                                                       const char* __restrict__ wp,
                                                       const int* __restrict__ bias,
                                                       float* __restrict__ out) {
    const int tid  = threadIdx.x;
    const int lane = tid & 63;
    const int wave = tid >> 6;
    const int l15  = lane & 15;
    const int quad = lane >> 4;
    const int bx = blockIdx.x;   // w tile (64 pixels)
    const int by = blockIdx.y;   // h tile (8 rows)
    const int n  = blockIdx.z;

    // A-frags (weights): m=cout=l15(+half*16), k-group=quad (16 int8 per lane). L2-resident.
    intx4 Af[3][2][2];
#pragma unroll
    for (int kh = 0; kh < 3; ++kh)
#pragma unroll
        for (int p = 0; p < 2; ++p)
#pragma unroll
            for (int hf = 0; hf < 2; ++hf)
                Af[kh][p][hf] = *(const intx4*)(wp + (((kh * 2 + p) * 32 + hf * 16 + l15) << 6) + quad * 16);

    int bi0[4], bi1[4];
#pragma unroll
    for (int r = 0; r < 4; ++r) { bi0[r] = bias[quad * 4 + r]; bi1[r] = bias[16 + quad * 4 + r]; }

    const int w0 = bx * 64 + wave * 16;      // this wave's 16 output pixels: w0 + l15
    const size_t rstride = (size_t)PW * CIN; // bytes per padded row
    const unsigned char* pbase = xq + (((size_t)n * PH + by * TH) * PW + (w0 + l15)) * CIN + quad * 16;

    // B-frags: n=pixel=l15, k-group=quad; pair p covers padded cols +2p,+2p+1 (64B span).
    intx4 Bf[10][2];
#pragma unroll
    for (int r = 0; r < 4; ++r)
#pragma unroll
        for (int p = 0; p < 2; ++p)
            Bf[r][p] = *(const intx4*)(pbase + r * rstride + p * 64);

#pragma unroll
    for (int it = 0; it < 4; ++it) {
        if (it < 3) {       // prefetch the 2 new input rows before this iter's stores
#pragma unroll
            for (int r = 0; r < 2; ++r)
#pragma unroll
                for (int p = 0; p < 2; ++p)
                    Bf[2 * it + 4 + r][p] = *(const intx4*)(pbase + (2 * it + 4 + r) * rstride + p * 64);
        }
        intx4 acc[2][2];
#pragma unroll
        for (int o = 0; o < 2; ++o)
#pragma unroll
            for (int hf = 0; hf < 2; ++hf)
                acc[o][hf] = (intx4){0, 0, 0, 0};
#pragma unroll
        for (int o = 0; o < 2; ++o)
#pragma unroll
            for (int kh = 0; kh < 3; ++kh)
#pragma unroll
                for (int p = 0; p < 2; ++p) {
                    const intx4 b = Bf[2 * it + o + kh][p];
                    acc[o][0] = __builtin_amdgcn_mfma_i32_16x16x64_i8(Af[kh][p][0], b, acc[o][0], 0, 0, 0);
                    acc[o][1] = __builtin_amdgcn_mfma_i32_16x16x64_i8(Af[kh][p][1], b, acc[o][1], 0, 0, 0);
                }
        // epilogue: D col(n=pixel)=l15, row(m=cout)=quad*4+r -> 16-lane contiguous stores
#pragma unroll
        for (int o = 0; o < 2; ++o) {
            const int h = by * TH + 2 * it + o;
            float* op0 = out + (((size_t)n * COUT + quad * 4) * HD + h) * WD + w0 + l15;
            float* op1 = op0 + (size_t)16 * HD * WD;
#pragma unroll
            for (int r = 0; r < 4; ++r) {
                int v0 = acc[o][0][r] + bi0[r];          // exact y_int
                float yq0 = rintf((float)v0 * 0.01f);
                yq0 = fminf(fmaxf(yq0, -127.f), 127.f);
                op0[(size_t)r * (HD * WD)] = fmaxf(yq0 * 0.1f, 0.f);
                int v1 = acc[o][1][r] + bi1[r];
                float yq1 = rintf((float)v1 * 0.01f);
                yq1 = fminf(fmaxf(yq1, -127.f), 127.f);
                op1[(size_t)r * (HD * WD)] = fmaxf(yq1 * 0.1f, 0.f);
            }
        }
    }
}

// ---------------- fallback (R1 fused kernel, known-good) if workspace too small ----------------
__launch_bounds__(256, 2)
__global__ void conv2d_int8_fused(const float* __restrict__ x,
                                  const int* __restrict__ wq,
                                  const int* __restrict__ bias,
                                  float* __restrict__ out)
{
    __shared__ unsigned short xs[10 * 66 * 32];
    __shared__ unsigned short ws[9 * 32 * 32];
    const int tid = threadIdx.x;
    const int bx = blockIdx.x, by = blockIdx.y, n = blockIdx.z;
    for (int i = tid; i < COUT * CIN * 9; i += 256) {
        int cout = i / 288, rem = i - cout * 288, cin = rem / 9, t = rem - cin * 9;
        float f = (float)(wq[i] - 128);
        ws[(t * 32 + cout) * 32 + cin] = (unsigned short)(__float_as_uint(f) >> 16);
    }
    const int h_base = by * TH - 1;
    const int w_base = bx * 64 - 1;
    for (int j = tid; j < CIN * 10 * 66; j += 256) {
        int c = j / 660, rem = j - c * 660, r = rem / 66, wc = rem - r * 66;
        int h = h_base + r, w = w_base + wc;
        float q = 0.0f;
        if ((unsigned)h < (unsigned)HD && (unsigned)w < (unsigned)WD) {
            float xv = x[((size_t)(n * CIN + c) * HD + h) * WD + w];
            q = rintf(xv / 0.05f);
            q = fminf(fmaxf(q, -128.0f), 127.0f);
        }
        unsigned short b = (unsigned short)(__float_as_uint(q) >> 16);
        int pix = r * 66 + wc;
        int grp = (c >> 3) ^ (pix & 3);
        xs[pix * 32 + (grp << 3) + (c & 7)] = b;
    }
    __syncthreads();
    const int lane = tid & 63, wave = tid >> 6;
    const int l15 = lane & 15, quad = lane >> 4;
    short8 bfrag[9][2];
#pragma unroll
    for (int t = 0; t < 9; ++t)
#pragma unroll
        for (int hf = 0; hf < 2; ++hf)
            bfrag[t][hf] = *(const short8*)&ws[(t * 32 + hf * 16 + l15) * 32 + quad * 8];
    const float b0 = (float)bias[l15];
    const float b1 = (float)bias[16 + l15];
    const int wseg = wave * 16;
    for (int hr = 0; hr < TH; ++hr) {
        floatx4 acc0 = {0.f, 0.f, 0.f, 0.f};
        floatx4 acc1 = {0.f, 0.f, 0.f, 0.f};
#pragma unroll
        for (int kh = 0; kh < 3; ++kh)
#pragma unroll
            for (int kw = 0; kw < 3; ++kw) {
                int pix = (hr + kh) * 66 + wseg + l15 + kw;
                int grp = quad ^ (pix & 3);
                short8 a = *(const short8*)&xs[pix * 32 + (grp << 3)];
                int t = kh * 3 + kw;
                acc0 = __builtin_amdgcn_mfma_f32_16x16x32_bf16(a, bfrag[t][0], acc0, 0, 0, 0);
                acc1 = __builtin_amdgcn_mfma_f32_16x16x32_bf16(a, bfrag[t][1], acc1, 0, 0, 0);
            }
        const int h_out = by * TH + hr;
        const int w_out0 = bx * 64 + wseg;
#pragma unroll
        for (int r = 0; r < 4; ++r) {
            int wo = w_out0 + quad * 4 + r;
            {
                float v = acc0[r] + b0;
                float yq = rintf(v * 0.01f);
                yq = fminf(fmaxf(yq, -127.f), 127.f);
                out[((size_t)(n * COUT + l15) * HD + h_out) * WD + wo] = fmaxf(yq * 0.1f, 0.f);
            }
            {
                float v = acc1[r] + b1;
                float yq = rintf(v * 0.01f);
                yq = fminf(fmaxf(yq, -127.f), 127.f);
                out[((size_t)(n * COUT + 16 + l15) * HD + h_out) * WD + wo] = fmaxf(yq * 0.1f, 0.f);
            }
        }
    }
}

extern "C" void kernel_launch(void* const* d_in, const int* in_sizes, int n_in,
                              void* d_out, int out_size, void* d_ws, size_t ws_size,
                              hipStream_t stream) {
    const float* x  = (const float*)d_in[0];
    const int*   wq = (const int*)d_in[1];
    const int*   bi = (const int*)d_in[2];
    float* out = (float*)d_out;

    if (ws_size >= WS_NEED) {
        unsigned char* xq = (unsigned char*)d_ws;
        char* wp = (char*)d_ws + XQ_BYTES + SLACK;
        aux8_kernel<<<(N_BORDER + N_WP + 255) / 256, 256, 0, stream>>>(wq, xq, wp);
        quant8_kernel<<<(N_IMG * HD * WD) / 256, 256, 0, stream>>>(x, xq);
        conv8_kernel<<<dim3(WD / 64, HD / TH, N_IMG), dim3(256), 0, stream>>>(xq, wp, bi, out);
    } else {
        conv2d_int8_fused<<<dim3(WD / 64, HD / TH, N_IMG), dim3(256), 0, stream>>>(x, wq, bi, out);
    }
}